// Round 2
// baseline (256.707 us; speedup 1.0000x reference)
//
#include <hip/hip_runtime.h>
#include <stdint.h>

typedef unsigned short u16;
typedef short short8 __attribute__((ext_vector_type(8)));
typedef short short4v __attribute__((ext_vector_type(4)));
typedef float float4v __attribute__((ext_vector_type(4)));
typedef float float16v __attribute__((ext_vector_type(16)));
typedef uint32_t uint2v __attribute__((ext_vector_type(2)));

#define HW 4096
#define QSCL 0.18033688011112042f   /* 0.125 * log2(e), folded into Q at conv time */

// async global->LDS DMA: per-lane global addr, LDS dest = wave-uniform base + lane*16
#define GLOAD_LDS(g, l) __builtin_amdgcn_global_load_lds( \
    (const __attribute__((address_space(1))) void*)(g),   \
    (__attribute__((address_space(3))) void*)(l), 16, 0, 0)

static __device__ __forceinline__ u16 f2bf(float f) {
  union { float f; uint32_t u; } v; v.f = f;
  uint32_t r = v.u + 0x7fffu + ((v.u >> 16) & 1u);
  return (u16)(r >> 16);
}

// packed f32x2 -> bf16x2 (RNE), single instruction; src0 -> low half
static __device__ __forceinline__ uint32_t pkbf(float a, float b) {
  uint32_t r;
  asm("v_cvt_pk_bf16_f32 %0, %1, %2" : "=v"(r) : "v"(a), "v"(b));
  return r;
}

// ---- kernel 1: x [4,256,4096] f32 -> Xtp [4,66,66,256] bf16 (spatially padded; halo pre-zeroed)
__global__ __launch_bounds__(256) void k_xt(const float* __restrict__ x, u16* __restrict__ Xtp) {
  __shared__ float t[32][33];
  const int b = blockIdx.z, c0 = blockIdx.y * 32, p0 = blockIdx.x * 32;
  const int tid = threadIdx.x;
  const int l8 = tid >> 5, lp = tid & 31;
#pragma unroll
  for (int i = 0; i < 4; i++) {
    int c = l8 + i * 8;
    t[c][lp] = x[(size_t)(b * 256 + c0 + c) * HW + p0 + lp];
  }
  __syncthreads();
#pragma unroll
  for (int i = 0; i < 4; i++) {
    int p = l8 + i * 8;
    int pp = p0 + p;
    int y = pp >> 6, xx = pp & 63;
    Xtp[((size_t)(b * 66 + y + 1) * 66 + (xx + 1)) * 256 + c0 + lp] = f2bf(t[lp][p]);
  }
}

// ---- kernel 2: repack weights -> Wt [9][384][256] bf16 (ci contiguous), bcat[384] f32
__global__ __launch_bounds__(256) void k_wprep(const float* __restrict__ qw, const float* __restrict__ qb,
    const float* __restrict__ kw, const float* __restrict__ kb,
    const float* __restrict__ vw, const float* __restrict__ vb,
    u16* __restrict__ Wt, float* __restrict__ bcat) {
  int tid = blockIdx.x * 256 + threadIdx.x;
  if (tid < 9 * 384 * 256) {
    int ci = tid & 255;
    int n = (tid >> 8) % 384;
    int off = tid / (384 * 256);
    float val;
    if (n < 64)       val = qw[(size_t)n * 2304 + ci * 9 + off];
    else if (n < 128) val = kw[(size_t)(n - 64) * 2304 + ci * 9 + off];
    else              val = vw[(size_t)(n - 128) * 2304 + ci * 9 + off];
    Wt[tid] = f2bf(val);
  }
  if (tid < 384) bcat[tid] = (tid < 64) ? qb[tid] : (tid < 128) ? kb[tid - 64] : vb[tid - 128];
}

// ---- kernel 3: fused QKV conv (proven structure; Q outputs pre-scaled by QSCL).
__global__ __launch_bounds__(256) void k_conv(const u16* __restrict__ Xtp,
    const u16* __restrict__ Wt, const float* __restrict__ bcat,
    u16* __restrict__ Qt, u16* __restrict__ Kt, u16* __restrict__ Vcf) {
  __shared__ __align__(16) u16 Als[2][128 * 64];   // 16 KB per buf [row pos][64 k]
  __shared__ __align__(16) u16 Bls[2][64 * 64];    // 8 KB per buf  [row ch ][64 k]
  const int tid = threadIdx.x;
  const int b = blockIdx.z, ct = blockIdx.y;       // ct: 0=Q, 1=K, 2..5=V slices
  const int p0 = blockIdx.x * 128, n0 = ct * 64;
  const int w = tid >> 6, lane = tid & 63, l16 = lane & 15, quad = lane >> 4;

  const int lr = lane >> 3, lcx = (lane & 7) ^ lr;
  const u16* ag[4];
#pragma unroll
  for (int g = 0; g < 4; g++) {
    const int pos = p0 + w * 32 + g * 8 + lr;
    const int py = pos >> 6, px = pos & 63;
    ag[g] = Xtp + ((size_t)(b * 66 + py) * 66 + px) * 256 + lcx * 8;
  }
  const u16* bg[2];
#pragma unroll
  for (int g = 0; g < 2; g++)
    bg[g] = Wt + (size_t)(n0 + w * 16 + g * 8 + lr) * 256 + lcx * 8;

  const int rx = l16 & 7;

  float4v acc[2][4];
  const float4v zz = {0.f, 0.f, 0.f, 0.f};
#pragma unroll
  for (int i = 0; i < 2; i++)
#pragma unroll
    for (int j = 0; j < 4; j++) acc[i][j] = zz;

#pragma unroll
  for (int g = 0; g < 4; g++) GLOAD_LDS(ag[g], &Als[0][(w * 32 + g * 8) * 64]);
#pragma unroll
  for (int g = 0; g < 2; g++) GLOAD_LDS(bg[g], &Bls[0][(w * 16 + g * 8) * 64]);
  __syncthreads();

  for (int ks = 0; ks < 36; ks++) {
    const int buf = ks & 1;
    if (ks + 1 < 36) {
      const int ksn = ks + 1, tap = ksn >> 2, cg = (ksn & 3) * 64;
      const int dy = (tap * 11) >> 5, dx = tap - dy * 3;
      const int aoff = (dy * 66 + dx) * 256 + cg;
      const size_t boff = (size_t)tap * 98304 + cg;
#pragma unroll
      for (int g = 0; g < 4; g++) GLOAD_LDS(ag[g] + aoff, &Als[buf ^ 1][(w * 32 + g * 8) * 64]);
#pragma unroll
      for (int g = 0; g < 2; g++) GLOAD_LDS(bg[g] + boff, &Bls[buf ^ 1][(w * 16 + g * 8) * 64]);
    }

    short8 af[2][2], bfv[4][2];
#pragma unroll
    for (int mt = 0; mt < 2; mt++)
#pragma unroll
      for (int kk = 0; kk < 2; kk++)
        af[mt][kk] = *(const short8*)&Als[buf][(w * 32 + mt * 16 + l16) * 64 + (((kk * 4 + quad) ^ rx) * 8)];
#pragma unroll
    for (int nt = 0; nt < 4; nt++)
#pragma unroll
      for (int kk = 0; kk < 2; kk++)
        bfv[nt][kk] = *(const short8*)&Bls[buf][(nt * 16 + l16) * 64 + (((kk * 4 + quad) ^ rx) * 8)];

    if (ct < 2) {
#pragma unroll
      for (int mt = 0; mt < 2; mt++)
#pragma unroll
        for (int nt = 0; nt < 4; nt++)
#pragma unroll
          for (int kk = 0; kk < 2; kk++)
            acc[mt][nt] = __builtin_amdgcn_mfma_f32_16x16x32_bf16(bfv[nt][kk], af[mt][kk], acc[mt][nt], 0, 0, 0);
    } else {
#pragma unroll
      for (int mt = 0; mt < 2; mt++)
#pragma unroll
        for (int nt = 0; nt < 4; nt++)
#pragma unroll
          for (int kk = 0; kk < 2; kk++)
            acc[mt][nt] = __builtin_amdgcn_mfma_f32_16x16x32_bf16(af[mt][kk], bfv[nt][kk], acc[mt][nt], 0, 0, 0);
    }
    __syncthreads();
  }

  if (ct < 2) {
    u16* base = (ct == 0) ? Qt : Kt;
    const float qs = (ct == 0) ? QSCL : 1.0f;
#pragma unroll
    for (int mt = 0; mt < 2; mt++) {
      const int p = p0 + w * 32 + mt * 16 + l16;
#pragma unroll
      for (int nt = 0; nt < 4; nt++) {
        const int nb = nt * 16 + quad * 4;
        short4v o;
#pragma unroll
        for (int r = 0; r < 4; r++) o[r] = (short)f2bf((acc[mt][nt][r] + bcat[ct * 64 + nb + r]) * qs);
        *(short4v*)(base + (size_t)(b * HW + p) * 64 + nb) = o;
      }
    }
  } else {
#pragma unroll
    for (int mt = 0; mt < 2; mt++) {
      const int pb = p0 + w * 32 + mt * 16 + quad * 4;
#pragma unroll
      for (int nt = 0; nt < 4; nt++) {
        const int cl = nt * 16 + l16;
        const int gc = (ct - 2) * 64 + cl;
        const float bias = bcat[ct * 64 + cl];
        short4v o;
#pragma unroll
        for (int r = 0; r < 4; r++) o[r] = (short)f2bf(acc[mt][nt][r] + bias);
        *(short4v*)(Vcf + (size_t)(b * 256 + gc) * HW + pb) = o;
      }
    }
  }
}

// ---- kernel 4: flash attention, R2 restructure (latency-bound fix).
// R1 lesson: 1 block/CU + 2 barriers/iter + everything-through-LDS = serialized
// critical path; all pipes <25% busy. R2:
//   * 32-query blocks -> grid 512 = 2 blocks/CU (true phase overlap across blocks).
//   * V NEVER staged in LDS: each PV wave owns a 32-channel block; its MFMA
//     A-fragment V[c][j] is 16B contiguous per lane -> global->register loads
//     issued at iter top (T14), consumed after the P barrier; S-phase hides L2
//     latency. Moves V off the saturated LDS pipe onto the idle TA/L1/L2 pipe.
//   * XCD-batch pinning: b = bid&3 -> round-robin XCD gets one batch; its 2MB
//     V slice stays L2-resident across the 16x refetch.
// Per wave-iter LDS: 2 K reads + 1 P write + 4 P reads, all 2-lane/bank (free).
// LDS 21 KB, ~90 VGPR (launch_bounds caps at 128 for 2-block residency).
__global__ __launch_bounds__(512, 4) void k_attn(const u16* __restrict__ Qt,
    const u16* __restrict__ Kt, const u16* __restrict__ Vcf, float* __restrict__ out) {
  __shared__ __align__(16) u16 Kls[2][64 * 64];     // 16 KB [j][d] swizzled, dbuf
  __shared__ __align__(16) u16 Pls[32 * 64];        //  4 KB [i][j] swizzled
  __shared__ float Lls[4][32];                      // per-jb partial row sums

  const int tid = threadIdx.x;
  const int bid = blockIdx.x;
  const int b = bid & 3, ib = (bid >> 2) * 32;      // XCD k -> batch k&3 (L2 pin)
  const int w = tid >> 6, lane = tid & 63;
  const int l16 = lane & 15, quad = lane >> 4;
  const int l32 = lane & 31, half = lane >> 5;
  const int jb = w & 3, ih = w >> 2;   // S-phase ownership: 16 j x 16 i
  // PV ownership: wave w -> channels w*32..w*32+31, all 32 i

  const u16* Kb = Kt + (size_t)b * HW * 64;

  // K staging lane constants: 8 rows x 8 chunks(16B); global chunk = (lane&7)^row
  const int lr = lane >> 3, lcx = (lane & 7) ^ lr;
  const size_t koff = (size_t)(w * 8 + lr) * 128 + (size_t)lcx * 16;

  // S-phase LDS read offsets (u16 units)
  const int krow = (jb * 16 + l16) * 64;
  const int kc0 = (quad ^ (l16 & 7)) * 8;
  const int kc1 = ((4 + quad) ^ (l16 & 7)) * 8;

  // P write offset (u16 units): row = ih*16+l16, col chunk jb*2+(quad>>1), half q&1
  const int pwo = (ih * 16 + l16) * 64 + (((jb * 2 + (quad >> 1)) ^ (l16 & 7)) * 8) + (quad & 1) * 4;

  // P read offsets per jk (u16 units): row = l32, col chunk jk*2+half
  int pro[4];
#pragma unroll
  for (int jk = 0; jk < 4; jk++)
    pro[jk] = l32 * 64 + (((jk * 2 + half) ^ (l32 & 7)) * 8);

  // V global per-lane base: V[c = w*32 + l32][j], 16B at j = jt*64 + jk*16 + half*8
  const char* vp = (const char*)Vcf + ((size_t)(b * 256 + w * 32 + l32)) * (HW * 2) + half * 16;

  // Q as B-operand: B[k=d=quad*8+kk*32+e][n=i=l16], rows i = ib + ih*16 + l16
  short8 qf0, qf1;
  {
    const u16* qp = Qt + ((size_t)(b * HW + ib + ih * 16 + l16)) * 64 + quad * 8;
    qf0 = *(const short8*)qp;
    qf1 = *(const short8*)(qp + 32);
  }

  float16v of;
#pragma unroll
  for (int r = 0; r < 16; r++) of[r] = 0.f;
  float lp = 0.f;
  const float4v zz = {0.f, 0.f, 0.f, 0.f};

  // ---- prologue: stage K tile 0 into buffer 0 (1 DMA per wave)
  GLOAD_LDS((const char*)Kb + koff, &Kls[0][(w * 8) * 64]);
  __syncthreads();

  for (int jt = 0; jt < 64; jt++) {
    const int buf = jt & 1;

    // ---- issue V register loads for THIS tile (consumed after barrier 1)
    short8 vf0 = *(const short8*)(vp);
    short8 vf1 = *(const short8*)(vp + 32);
    short8 vf2 = *(const short8*)(vp + 64);
    short8 vf3 = *(const short8*)(vp + 96);

    // ---- stage next K tile into buf^1 (DMA overlaps this iteration)
    {
      const int jn = ((jt + 1) & 63) * 64;
      GLOAD_LDS((const char*)Kb + (size_t)jn * 128 + koff, &Kls[buf ^ 1][(w * 8) * 64]);
    }

    // ---- S^T tile: lane holds S^T[j = jb*16+quad*4+r][i = ih*16+l16]
    short8 k0 = *(const short8*)&Kls[buf][krow + kc0];
    short8 k1 = *(const short8*)&Kls[buf][krow + kc1];
    float4v s = zz;
    s = __builtin_amdgcn_mfma_f32_16x16x32_bf16(k0, qf0, s, 0, 0, 0);
    s = __builtin_amdgcn_mfma_f32_16x16x32_bf16(k1, qf1, s, 0, 0, 0);

    // ---- P = exp2(S) (Q pre-scaled); pack; swizzled write; per-lane partial sum
    {
      float p0 = exp2f(s[0]), p1 = exp2f(s[1]), p2 = exp2f(s[2]), p3 = exp2f(s[3]);
      lp += (p0 + p1) + (p2 + p3);
      uint2v pd; pd[0] = pkbf(p0, p1); pd[1] = pkbf(p2, p3);
      *(uint2v*)&Pls[pwo] = pd;
    }

    // ---- barrier 1: cross-wave P handoff (lgkm only — K DMA + V loads in flight)
    __builtin_amdgcn_sched_barrier(0);
    asm volatile("s_waitcnt lgkmcnt(0)" ::: "memory");
    __builtin_amdgcn_s_barrier();
    __builtin_amdgcn_sched_barrier(0);

    // ---- O^T += V P : D[m = c offset][n = i = l32], V from registers
    __builtin_amdgcn_s_setprio(1);
    {
      short8 pf0 = *(const short8*)&Pls[pro[0]];
      of = __builtin_amdgcn_mfma_f32_32x32x16_bf16(vf0, pf0, of, 0, 0, 0);
      short8 pf1 = *(const short8*)&Pls[pro[1]];
      of = __builtin_amdgcn_mfma_f32_32x32x16_bf16(vf1, pf1, of, 0, 0, 0);
      short8 pf2 = *(const short8*)&Pls[pro[2]];
      of = __builtin_amdgcn_mfma_f32_32x32x16_bf16(vf2, pf2, of, 0, 0, 0);
      short8 pf3 = *(const short8*)&Pls[pro[3]];
      of = __builtin_amdgcn_mfma_f32_32x32x16_bf16(vf3, pf3, of, 0, 0, 0);
    }
    __builtin_amdgcn_s_setprio(0);

    __syncthreads();   // P reads done; next K tile landed
    vp += 128;
  }

  // ---- epilogue: finish row sums (quad reduce + cross-jb via LDS), scale, store
  lp += __shfl_xor(lp, 16);
  lp += __shfl_xor(lp, 32);
  if (quad == 0) Lls[jb][ih * 16 + l16] = lp;
  __syncthreads();

  const float inv = 1.0f / ((Lls[0][l32] + Lls[1][l32]) + (Lls[2][l32] + Lls[3][l32]));
  float* ob = out + ((size_t)(b * 256 + w * 32 + 4 * half)) * HW + ib + l32;
#pragma unroll
  for (int r = 0; r < 16; r++)
    ob[(size_t)((r & 3) + 8 * (r >> 2)) * HW] = of[r] * inv;
}

extern "C" void kernel_launch(void* const* d_in, const int* in_sizes, int n_in,
                              void* d_out, int out_size, void* d_ws, size_t ws_size,
                              hipStream_t stream) {
  const float* x  = (const float*)d_in[0];
  const float* qw = (const float*)d_in[1];
  const float* qb = (const float*)d_in[2];
  const float* kw = (const float*)d_in[3];
  const float* kb = (const float*)d_in[4];
  const float* vw = (const float*)d_in[5];
  const float* vb = (const float*)d_in[6];
  float* out = (float*)d_out;
  char* ws = (char*)d_ws;
  u16*   Xtp = (u16*)(ws);
  u16*   Wt  = (u16*)(ws + 8921088);
  float* bc  = (float*)(ws + 10690560);
  u16*   Qt  = (u16*)(ws + 10692096);
  u16*   Kt  = (u16*)(ws + 12789248);
  u16*   Vcf = (u16*)(ws + 14886400);

  hipMemsetAsync(Xtp, 0, 8921088, stream);  // zero the spatial halo
  k_xt  <<<dim3(128, 8, 4), 256, 0, stream>>>(x, Xtp);
  k_wprep<<<3456, 256, 0, stream>>>(qw, qb, kw, kb, vw, vb, Wt, bc);
  k_conv<<<dim3(32, 6, 4), 256, 0, stream>>>(Xtp, Wt, bc, Qt, Kt, Vcf);
  k_attn<<<512, 512, 0, stream>>>(Qt, Kt, Vcf, out);
}

// Round 4
// 204.589 us; speedup vs baseline: 1.2547x; 1.2547x over previous
//
#include <hip/hip_runtime.h>
#include <stdint.h>

typedef unsigned short u16;
typedef short short8 __attribute__((ext_vector_type(8)));
typedef short short4v __attribute__((ext_vector_type(4)));
typedef float float4v __attribute__((ext_vector_type(4)));
typedef float float16v __attribute__((ext_vector_type(16)));
typedef uint32_t uint2v __attribute__((ext_vector_type(2)));

#define HW 4096
#define QSCL 0.18033688011112042f   /* 0.125 * log2(e), folded into Q at conv time */

// async global->LDS DMA: per-lane global addr, LDS dest = wave-uniform base + lane*16
#define GLOAD_LDS(g, l) __builtin_amdgcn_global_load_lds( \
    (const __attribute__((address_space(1))) void*)(g),   \
    (__attribute__((address_space(3))) void*)(l), 16, 0, 0)

static __device__ __forceinline__ u16 f2bf(float f) {
  union { float f; uint32_t u; } v; v.f = f;
  uint32_t r = v.u + 0x7fffu + ((v.u >> 16) & 1u);
  return (u16)(r >> 16);
}

// packed f32x2 -> bf16x2 (RNE), single instruction; src0 -> low half
static __device__ __forceinline__ uint32_t pkbf(float a, float b) {
  uint32_t r;
  asm("v_cvt_pk_bf16_f32 %0, %1, %2" : "=v"(r) : "v"(a), "v"(b));
  return r;
}

// ---- kernel 1: x [4,256,4096] f32 -> Xtp [4,66,66,256] bf16 (spatially padded; halo pre-zeroed)
__global__ __launch_bounds__(256) void k_xt(const float* __restrict__ x, u16* __restrict__ Xtp) {
  __shared__ float t[32][33];
  const int b = blockIdx.z, c0 = blockIdx.y * 32, p0 = blockIdx.x * 32;
  const int tid = threadIdx.x;
  const int l8 = tid >> 5, lp = tid & 31;
#pragma unroll
  for (int i = 0; i < 4; i++) {
    int c = l8 + i * 8;
    t[c][lp] = x[(size_t)(b * 256 + c0 + c) * HW + p0 + lp];
  }
  __syncthreads();
#pragma unroll
  for (int i = 0; i < 4; i++) {
    int p = l8 + i * 8;
    int pp = p0 + p;
    int y = pp >> 6, xx = pp & 63;
    Xtp[((size_t)(b * 66 + y + 1) * 66 + (xx + 1)) * 256 + c0 + lp] = f2bf(t[lp][p]);
  }
}

// ---- kernel 2: repack weights -> Wt [9][384][256] bf16 (ci contiguous), bcat[384] f32
__global__ __launch_bounds__(256) void k_wprep(const float* __restrict__ qw, const float* __restrict__ qb,
    const float* __restrict__ kw, const float* __restrict__ kb,
    const float* __restrict__ vw, const float* __restrict__ vb,
    u16* __restrict__ Wt, float* __restrict__ bcat) {
  int tid = blockIdx.x * 256 + threadIdx.x;
  if (tid < 9 * 384 * 256) {
    int ci = tid & 255;
    int n = (tid >> 8) % 384;
    int off = tid / (384 * 256);
    float val;
    if (n < 64)       val = qw[(size_t)n * 2304 + ci * 9 + off];
    else if (n < 128) val = kw[(size_t)(n - 64) * 2304 + ci * 9 + off];
    else              val = vw[(size_t)(n - 128) * 2304 + ci * 9 + off];
    Wt[tid] = f2bf(val);
  }
  if (tid < 384) bcat[tid] = (tid < 64) ? qb[tid] : (tid < 128) ? kb[tid - 64] : vb[tid - 128];
}

// ---- kernel 3: fused QKV conv (proven structure; Q outputs pre-scaled by QSCL).
__global__ __launch_bounds__(256) void k_conv(const u16* __restrict__ Xtp,
    const u16* __restrict__ Wt, const float* __restrict__ bcat,
    u16* __restrict__ Qt, u16* __restrict__ Kt, u16* __restrict__ Vcf) {
  __shared__ __align__(16) u16 Als[2][128 * 64];   // 16 KB per buf [row pos][64 k]
  __shared__ __align__(16) u16 Bls[2][64 * 64];    // 8 KB per buf  [row ch ][64 k]
  const int tid = threadIdx.x;
  const int b = blockIdx.z, ct = blockIdx.y;       // ct: 0=Q, 1=K, 2..5=V slices
  const int p0 = blockIdx.x * 128, n0 = ct * 64;
  const int w = tid >> 6, lane = tid & 63, l16 = lane & 15, quad = lane >> 4;

  const int lr = lane >> 3, lcx = (lane & 7) ^ lr;
  const u16* ag[4];
#pragma unroll
  for (int g = 0; g < 4; g++) {
    const int pos = p0 + w * 32 + g * 8 + lr;
    const int py = pos >> 6, px = pos & 63;
    ag[g] = Xtp + ((size_t)(b * 66 + py) * 66 + px) * 256 + lcx * 8;
  }
  const u16* bg[2];
#pragma unroll
  for (int g = 0; g < 2; g++)
    bg[g] = Wt + (size_t)(n0 + w * 16 + g * 8 + lr) * 256 + lcx * 8;

  const int rx = l16 & 7;

  float4v acc[2][4];
  const float4v zz = {0.f, 0.f, 0.f, 0.f};
#pragma unroll
  for (int i = 0; i < 2; i++)
#pragma unroll
    for (int j = 0; j < 4; j++) acc[i][j] = zz;

#pragma unroll
  for (int g = 0; g < 4; g++) GLOAD_LDS(ag[g], &Als[0][(w * 32 + g * 8) * 64]);
#pragma unroll
  for (int g = 0; g < 2; g++) GLOAD_LDS(bg[g], &Bls[0][(w * 16 + g * 8) * 64]);
  __syncthreads();

  for (int ks = 0; ks < 36; ks++) {
    const int buf = ks & 1;
    if (ks + 1 < 36) {
      const int ksn = ks + 1, tap = ksn >> 2, cg = (ksn & 3) * 64;
      const int dy = (tap * 11) >> 5, dx = tap - dy * 3;
      const int aoff = (dy * 66 + dx) * 256 + cg;
      const size_t boff = (size_t)tap * 98304 + cg;
#pragma unroll
      for (int g = 0; g < 4; g++) GLOAD_LDS(ag[g] + aoff, &Als[buf ^ 1][(w * 32 + g * 8) * 64]);
#pragma unroll
      for (int g = 0; g < 2; g++) GLOAD_LDS(bg[g] + boff, &Bls[buf ^ 1][(w * 16 + g * 8) * 64]);
    }

    short8 af[2][2], bfv[4][2];
#pragma unroll
    for (int mt = 0; mt < 2; mt++)
#pragma unroll
      for (int kk = 0; kk < 2; kk++)
        af[mt][kk] = *(const short8*)&Als[buf][(w * 32 + mt * 16 + l16) * 64 + (((kk * 4 + quad) ^ rx) * 8)];
#pragma unroll
    for (int nt = 0; nt < 4; nt++)
#pragma unroll
      for (int kk = 0; kk < 2; kk++)
        bfv[nt][kk] = *(const short8*)&Bls[buf][(nt * 16 + l16) * 64 + (((kk * 4 + quad) ^ rx) * 8)];

    if (ct < 2) {
#pragma unroll
      for (int mt = 0; mt < 2; mt++)
#pragma unroll
        for (int nt = 0; nt < 4; nt++)
#pragma unroll
          for (int kk = 0; kk < 2; kk++)
            acc[mt][nt] = __builtin_amdgcn_mfma_f32_16x16x32_bf16(bfv[nt][kk], af[mt][kk], acc[mt][nt], 0, 0, 0);
    } else {
#pragma unroll
      for (int mt = 0; mt < 2; mt++)
#pragma unroll
        for (int nt = 0; nt < 4; nt++)
#pragma unroll
          for (int kk = 0; kk < 2; kk++)
            acc[mt][nt] = __builtin_amdgcn_mfma_f32_16x16x32_bf16(af[mt][kk], bfv[nt][kk], acc[mt][nt], 0, 0, 0);
    }
    __syncthreads();
  }

  if (ct < 2) {
    u16* base = (ct == 0) ? Qt : Kt;
    const float qs = (ct == 0) ? QSCL : 1.0f;
#pragma unroll
    for (int mt = 0; mt < 2; mt++) {
      const int p = p0 + w * 32 + mt * 16 + l16;
#pragma unroll
      for (int nt = 0; nt < 4; nt++) {
        const int nb = nt * 16 + quad * 4;
        short4v o;
#pragma unroll
        for (int r = 0; r < 4; r++) o[r] = (short)f2bf((acc[mt][nt][r] + bcat[ct * 64 + nb + r]) * qs);
        *(short4v*)(base + (size_t)(b * HW + p) * 64 + nb) = o;
      }
    }
  } else {
#pragma unroll
    for (int mt = 0; mt < 2; mt++) {
      const int pb = p0 + w * 32 + mt * 16 + quad * 4;
#pragma unroll
      for (int nt = 0; nt < 4; nt++) {
        const int cl = nt * 16 + l16;
        const int gc = (ct - 2) * 64 + cl;
        const float bias = bcat[ct * 64 + cl];
        short4v o;
#pragma unroll
        for (int r = 0; r < 4; r++) o[r] = (short)f2bf(acc[mt][nt][r] + bias);
        *(short4v*)(Vcf + (size_t)(b * 256 + gc) * HW + pb) = o;
      }
    }
  }
}

// ---- kernel 4: flash attention, R3 = R1 dataflow + single-barrier pipeline.
// R1 lesson: dataflow fine, two full-drain barriers/iter at 1 block/CU = lockstep
// idle (all pipes <25%). R2 lesson: V-in-reg thrashes L1 (8KB-stride 16B/lane);
// keep V via DMA staging; keep R2's XCD-batch pinning (FETCH 42.6->11.3 MB).
// R3 structure (64 q x 256 ch per 512-thread block, grid 256 = 1 block/CU):
//   triple-buffered K/V slots + double-buffered P; ONE __syncthreads per j-tile.
//   iter t: S(t) reads K slot t%3 -> P(t) write buf t&1 -> BARRIER (vmcnt+lgkm
//   drain) -> issue DMA(t+2) into slot (t+2)%3 -> PV(t) reads P buf t&1 + V slot
//   t%3. Slot (t+2)%3's last reader provably passed the previous barrier (PV(t-1)
//   finished before barrier(t)), so no race; each DMA gets ~a full iteration of
//   cover before the next barrier's drain. Waves spread around the loop ring ->
//   DS/MFMA/VALU/trans overlap across waves instead of barrier-lockstep.
// LDS 137 KB (1 block/CU by design).
__global__ __launch_bounds__(512, 2) void k_attn(const u16* __restrict__ Qt,
    const u16* __restrict__ Kt, const u16* __restrict__ Vcf, float* __restrict__ out) {
  __shared__ __align__(16) u16 Kls[3 * 4096];    // 24 KB: 3 slots [j 64][d 64] swizzled
  __shared__ __align__(16) u16 Vls[3 * 16384];   // 96 KB: 3 slots [c 256][j 64] swizzled
  __shared__ __align__(16) u16 Pls[2 * 4096];    // 16 KB: 2 bufs  [i 64][j 64] swizzled
  __shared__ float Lls[4][64];                   // per-jb partial row sums

  const int tid = threadIdx.x;
  const int bid = blockIdx.x;
  const int b = bid & 3, ib = (bid >> 2) * 64;   // XCD k -> batch k&3 (L2 pin)
  const int w = tid >> 6, lane = tid & 63;
  const int l16 = lane & 15, quad = lane >> 4;
  const int l32 = lane & 31, half = lane >> 5;
  const int jb = w & 3, ih = w >> 2;   // S-phase: wave w -> 16 j x 32 i
  // PV-phase: wave w -> channels w*32..w*32+31, all 64 i

  const char* Kb = (const char*)(Kt + (size_t)b * HW * 64);
  const char* Vb = (const char*)(Vcf + (size_t)b * 256 * HW);

  // staging lane constants: 8 rows x 8 chunks(16B); global chunk = (lane&7)^row
  const int lr = lane >> 3, lcx = (lane & 7) ^ lr;
  const int koff = (w * 8 + lr) * 128 + lcx * 16;               // K tile-local bytes
  const char* vbase = Vb + (size_t)(w * 32 + lr) * (HW * 2) + lcx * 16;
  const int kd = w * 8 * 64;                                    // K DMA dest (u16)

  // S-phase LDS read offsets (u16 units)
  const int krow = (jb * 16 + l16) * 64;
  const int kc0 = (quad ^ (l16 & 7)) * 8;
  const int kc1 = ((4 + quad) ^ (l16 & 7)) * 8;

  // P write offsets (u16): rows ih*32+l16 and +16, chunk (jb*2+(quad>>1))^(row&7)
  const int pw0 = (ih * 32 + l16) * 64 + (((jb * 2 + (quad >> 1)) ^ (l16 & 7)) * 8) + (quad & 1) * 4;
  const int pw1 = pw0 + 16 * 64;

  // PV-phase LDS read offsets (u16)
  const int rx5 = l32 & 7;
  const int vrow = (w * 32 + l32) * 64;
  const int prow0 = l32 * 64, prow1 = prow0 + 32 * 64;

  // Q as B-operand: B[k=d][n=i], rows i = ib + ih*32 + {0,16} + l16 (pre-scaled)
  short8 qf[2][2];
  {
    const u16* qp = Qt + ((size_t)(b * HW + ib + ih * 32 + l16)) * 64 + quad * 8;
    qf[0][0] = *(const short8*)qp;
    qf[0][1] = *(const short8*)(qp + 32);
    qf[1][0] = *(const short8*)(qp + 1024);
    qf[1][1] = *(const short8*)(qp + 1056);
  }

  float16v of0, of1;
#pragma unroll
  for (int r = 0; r < 16; r++) { of0[r] = 0.f; of1[r] = 0.f; }
  float lp0 = 0.f, lp1 = 0.f;
  const float4v zz = {0.f, 0.f, 0.f, 0.f};

  // ---- prologue: tiles 0,1 -> slots 0,1 (10 DMAs/wave), then drain
  GLOAD_LDS(Kb + koff, &Kls[kd]);
  GLOAD_LDS(Kb + 8192 + koff, &Kls[4096 + kd]);
#pragma unroll
  for (int g = 0; g < 4; g++)
    GLOAD_LDS(vbase + (size_t)(g * 8) * (HW * 2), &Vls[(w * 32 + g * 8) * 64]);
#pragma unroll
  for (int g = 0; g < 4; g++)
    GLOAD_LDS(vbase + (size_t)(g * 8) * (HW * 2) + 128, &Vls[16384 + (w * 32 + g * 8) * 64]);
  __syncthreads();

  int oKa = 0, oKb = 4096, oKc = 8192;        // current / in-flight / DMA-target
  int oVa = 0, oVb = 16384, oVc = 32768;

  for (int jt = 0; jt < 64; jt++) {
    const int po = (jt & 1) ? 4096 : 0;

    // ---- S^T tiles: lane holds S^T[j = jb*16+quad*4+r][i = ih*32+{0,16}+l16]
    short8 k0 = *(const short8*)&Kls[oKa + krow + kc0];
    short8 k1 = *(const short8*)&Kls[oKa + krow + kc1];
    float4v s0 = zz, s1 = zz;
    s0 = __builtin_amdgcn_mfma_f32_16x16x32_bf16(k0, qf[0][0], s0, 0, 0, 0);
    s0 = __builtin_amdgcn_mfma_f32_16x16x32_bf16(k1, qf[0][1], s0, 0, 0, 0);
    s1 = __builtin_amdgcn_mfma_f32_16x16x32_bf16(k0, qf[1][0], s1, 0, 0, 0);
    s1 = __builtin_amdgcn_mfma_f32_16x16x32_bf16(k1, qf[1][1], s1, 0, 0, 0);

    // ---- P = exp2(S) (Q pre-scaled); pack; swizzled write; per-lane partials
    {
      float p0 = exp2f(s0[0]), p1 = exp2f(s0[1]), p2 = exp2f(s0[2]), p3 = exp2f(s0[3]);
      lp0 += (p0 + p1) + (p2 + p3);
      uint2v pd; pd[0] = pkbf(p0, p1); pd[1] = pkbf(p2, p3);
      *(uint2v*)&Pls[po + pw0] = pd;
    }
    {
      float p0 = exp2f(s1[0]), p1 = exp2f(s1[1]), p2 = exp2f(s1[2]), p3 = exp2f(s1[3]);
      lp1 += (p0 + p1) + (p2 + p3);
      uint2v pd; pd[0] = pkbf(p0, p1); pd[1] = pkbf(p2, p3);
      *(uint2v*)&Pls[po + pw1] = pd;
    }

    // ---- the ONE barrier: P visible to all waves; prior DMAs landed (vmcnt+lgkm)
    __syncthreads();

    // ---- issue DMA for tile jt+2 into the just-freed slot (full-iter latency cover)
    if (jt < 62) {
      GLOAD_LDS(Kb + (size_t)(jt + 2) * 8192 + koff, &Kls[oKc + kd]);
      const char* vt = vbase + (size_t)(jt + 2) * 128;
#pragma unroll
      for (int g = 0; g < 4; g++)
        GLOAD_LDS(vt + (size_t)(g * 8) * (HW * 2), &Vls[oVc + (w * 32 + g * 8) * 64]);
    }

    // ---- O^T += V P : D[m = c][n = i], 2 i-halves, V read shared
    __builtin_amdgcn_s_setprio(1);
#pragma unroll
    for (int jk = 0; jk < 4; jk++) {
      const int co = ((jk * 2 + half) ^ rx5) * 8;
      short8 vf  = *(const short8*)&Vls[oVa + vrow + co];
      short8 pf0 = *(const short8*)&Pls[po + prow0 + co];
      short8 pf1 = *(const short8*)&Pls[po + prow1 + co];
      of0 = __builtin_amdgcn_mfma_f32_32x32x16_bf16(vf, pf0, of0, 0, 0, 0);
      of1 = __builtin_amdgcn_mfma_f32_32x32x16_bf16(vf, pf1, of1, 0, 0, 0);
    }
    __builtin_amdgcn_s_setprio(0);

    // ---- rotate slots: (cur, inflight, target) <- (inflight, target, cur)
    int t1 = oKa; oKa = oKb; oKb = oKc; oKc = t1;
    int t2 = oVa; oVa = oVb; oVb = oVc; oVc = t2;
  }

  // ---- epilogue: finish row sums (quad reduce + cross-jb via LDS), scale, store
  lp0 += __shfl_xor(lp0, 16); lp0 += __shfl_xor(lp0, 32);
  lp1 += __shfl_xor(lp1, 16); lp1 += __shfl_xor(lp1, 32);
  if (quad == 0) {
    Lls[jb][ih * 32 + l16] = lp0;
    Lls[jb][ih * 32 + 16 + l16] = lp1;
  }
  __syncthreads();

#pragma unroll
  for (int it = 0; it < 2; it++) {
    const int ii = it * 32 + l32;
    const float inv = 1.0f / ((Lls[0][ii] + Lls[1][ii]) + (Lls[2][ii] + Lls[3][ii]));
    float* ob = out + (size_t)(b * 256 + w * 32 + 4 * half) * HW + ib + ii;
    const float16v o = it ? of1 : of0;
#pragma unroll
    for (int r = 0; r < 16; r++)
      ob[(size_t)((r & 3) + 8 * (r >> 2)) * HW] = o[r] * inv;
  }
}

extern "C" void kernel_launch(void* const* d_in, const int* in_sizes, int n_in,
                              void* d_out, int out_size, void* d_ws, size_t ws_size,
                              hipStream_t stream) {
  const float* x  = (const float*)d_in[0];
  const float* qw = (const float*)d_in[1];
  const float* qb = (const float*)d_in[2];
  const float* kw = (const float*)d_in[3];
  const float* kb = (const float*)d_in[4];
  const float* vw = (const float*)d_in[5];
  const float* vb = (const float*)d_in[6];
  float* out = (float*)d_out;
  char* ws = (char*)d_ws;
  u16*   Xtp = (u16*)(ws);
  u16*   Wt  = (u16*)(ws + 8921088);
  float* bc  = (float*)(ws + 10690560);
  u16*   Qt  = (u16*)(ws + 10692096);
  u16*   Kt  = (u16*)(ws + 12789248);
  u16*   Vcf = (u16*)(ws + 14886400);

  hipMemsetAsync(Xtp, 0, 8921088, stream);  // zero the spatial halo
  k_xt  <<<dim3(128, 8, 4), 256, 0, stream>>>(x, Xtp);
  k_wprep<<<3456, 256, 0, stream>>>(qw, qb, kw, kb, vw, vb, Wt, bc);
  k_conv<<<dim3(32, 6, 4), 256, 0, stream>>>(Xtp, Wt, bc, Qt, Kt, Vcf);
  k_attn<<<256, 512, 0, stream>>>(Qt, Kt, Vcf, out);
}